// Round 7
// baseline (127.257 us; speedup 1.0000x reference)
//
#include <hip/hip_runtime.h>

constexpr int BATCH = 1048576;
constexpr int H = 20;       // hidden
constexpr int BLK = 256;    // threads per block = batch rows per block
constexpr int RS = 21;      // padded LDS row stride (gcd(21,32)=1 -> conflict-free)
constexpr int TILE = BLK * H;   // 5120 floats per tile

// packed-weight layout in d_ws (floats) — identical to validated R5/R6:
constexpr int WHH_OFF = 0;
constexpr int WIH_OFF = 1600;
constexpr int B_OFF   = 1760;

typedef float v2f __attribute__((ext_vector_type(2)));
__device__ __forceinline__ v2f splat2(float s) { v2f r; r.x = s; r.y = s; return r; }

// ---- exact path (bit-compatible with validated R3/R5/R6 kernels) ----
__device__ __forceinline__ float sigmoidf_stable(float z) {
    const float e = expf(-fabsf(z));
    const float n = (z >= 0.0f) ? 1.0f : e;
    return n / (1.0f + e);
}

// ---- fast path: native exp / rcp (validated R6) ----
__device__ __forceinline__ float fsigmoid(float z) {
    const float e = __expf(-z);
    return __builtin_amdgcn_rcpf(1.0f + e);
}
__device__ __forceinline__ float ftanh(float z) {
    const float e = __expf(2.0f * z);
    return 1.0f - 2.0f * __builtin_amdgcn_rcpf(e + 1.0f);
}

constexpr float EPS_GUARD = 1e-4f;

__global__ __launch_bounds__(256) void pack_weights(
    const float* __restrict__ W_ih, const float* __restrict__ W_hh,
    const float* __restrict__ b_ih, const float* __restrict__ b_hh,
    float* __restrict__ ws)
{
    const int i = blockIdx.x * 256 + threadIdx.x;
    if (i < 400) {
        const int q = i / 20, k = i % 20;
#pragma unroll
        for (int g = 0; g < 4; ++g)
            ws[WHH_OFF + i * 4 + g] = W_hh[(g * 20 + q) * 20 + k];
    }
    if (i < 20) {
#pragma unroll
        for (int g = 0; g < 4; ++g) {
            ws[WIH_OFF + i * 8 + g]     = W_ih[(g * 20 + i) * 2 + 0];
            ws[WIH_OFF + i * 8 + 4 + g] = W_ih[(g * 20 + i) * 2 + 1];
            ws[B_OFF   + i * 4 + g]     = b_ih[g * 20 + i] + b_hh[g * 20 + i];
        }
    }
}

__global__ __launch_bounds__(BLK, 5) void lstm_coord_kernel(
    const float* __restrict__ x,
    const float* __restrict__ hx,
    const float* __restrict__ cx,
    const float* __restrict__ u,
    const float* __restrict__ wsp,
    const float* __restrict__ W_dec,
    const float* __restrict__ b_dec,
    float* __restrict__ out)
{
    // single reused tile buffer: hx -> cx -> h -> c  (21504 B)
    __shared__ float sT[BLK * RS];

    const int t = threadIdx.x;
    const size_t base = (size_t)blockIdx.x * TILE;
    const int b = blockIdx.x * BLK + t;
    const int row = t * RS;

    // ---- stage hx tile (coalesced float4 -> padded LDS) ----
#pragma unroll
    for (int j = 0; j < 5; ++j) {
        const int g = 4 * (t + BLK * j);
        float4 v = *reinterpret_cast<const float4*>(hx + base + g);
#pragma unroll
        for (int e = 0; e < 4; ++e) {
            const int gg = g + e;
            sT[gg + gg / H] = (&v.x)[e];
        }
    }
    __syncthreads();

    // own-row hx -> splatted v2f registers (kept live for exact fallback)
    v2f hv2[H];
#pragma unroll
    for (int k = 0; k < H; ++k) hv2[k] = splat2(sT[row + k]);
    __syncthreads();   // all hv reads done before overwrite

    // ---- stage cx tile into the same buffer ----
#pragma unroll
    for (int j = 0; j < 5; ++j) {
        const int g = 4 * (t + BLK * j);
        float4 v = *reinterpret_cast<const float4*>(cx + base + g);
#pragma unroll
        for (int e = 0; e < 4; ++e) {
            const int gg = g + e;
            sT[gg + gg / H] = (&v.x)[e];
        }
    }
    __syncthreads();

    // own-row cx -> registers; from here on each thread touches only its row
    float cv[H];
#pragma unroll
    for (int k = 0; k < H; ++k) cv[k] = sT[row + k];

    const float2 xv = *reinterpret_cast<const float2*>(x + 2 * (size_t)b);
    const v2f x0v = splat2(xv.x);
    const v2f x1v = splat2(xv.y);
    const float uv = u[b];

    // ---- FAST path: LSTM cell + fused decode (bit-identical arithmetic to R6) ----
    float l0 = b_dec[0], l1 = b_dec[1], l2 = b_dec[2];
#pragma unroll
    for (int q = 0; q < H; ++q) {
        v2f g01 = *reinterpret_cast<const v2f*>(wsp + B_OFF + 4 * q);
        v2f g23 = *reinterpret_cast<const v2f*>(wsp + B_OFF + 4 * q + 2);
        g01 = g01 + x0v * *reinterpret_cast<const v2f*>(wsp + WIH_OFF + 8 * q);
        g23 = g23 + x0v * *reinterpret_cast<const v2f*>(wsp + WIH_OFF + 8 * q + 2);
        g01 = g01 + x1v * *reinterpret_cast<const v2f*>(wsp + WIH_OFF + 8 * q + 4);
        g23 = g23 + x1v * *reinterpret_cast<const v2f*>(wsp + WIH_OFF + 8 * q + 6);
#pragma unroll
        for (int k = 0; k < H; ++k) {
            const v2f wp01 = *reinterpret_cast<const v2f*>(wsp + WHH_OFF + (q * 20 + k) * 4);
            const v2f wp23 = *reinterpret_cast<const v2f*>(wsp + WHH_OFF + (q * 20 + k) * 4 + 2);
            g01 = g01 + hv2[k] * wp01;
            g23 = g23 + hv2[k] * wp23;
        }
        const float gi = fsigmoid(g01.x);
        const float gf = fsigmoid(g01.y);
        const float gg = ftanh(g23.x);
        const float go = fsigmoid(g23.y);
        const float cq = gf * cv[q] + gi * gg;
        const float hq = go * ftanh(cq);
        cv[q] = cq;             // registers now
        sT[row + q] = hq;       // own row only
        l0 += hq * W_dec[q];
        l1 += hq * W_dec[20 + q];
        l2 += hq * W_dec[40 + q];
    }

    // ---- fast softmax + inverse-CDF sample ----
    const float m = fmaxf(fmaxf(l0, l1), l2);
    const float s = __expf(l0 - m) + __expf(l1 - m) + __expf(l2 - m);
    const float lse = m + __logf(s);
    const float lp0 = l0 - lse, lp1 = l1 - lse, lp2 = l2 - lse;
    const float p0 = __expf(lp0), p1 = __expf(lp1), p2 = __expf(lp2);
    const float c0 = p0;
    const float c1 = c0 + p1;
    const float c2 = c1 + p2;
    int acti = (int)(c0 < uv) + (int)(c1 < uv) + (int)(c2 < uv);
    acti = acti > 2 ? 2 : acti;
    float act = (float)acti;
    float slp = (acti == 0) ? lp0 : ((acti == 1) ? lp1 : lp2);

    // ---- guard: near a fast-cdf boundary -> redo with exact libm path ----
    const float d0 = fabsf(c0 - uv), d1 = fabsf(c1 - uv), d2 = fabsf(c2 - uv);
    const bool risky = fminf(fminf(d0, d1), d2) < EPS_GUARD;
    if (risky) {
        const float* cxr = cx + (size_t)b * H;   // original cx
        float l0e = b_dec[0], l1e = b_dec[1], l2e = b_dec[2];
#pragma unroll 1
        for (int q = 0; q < H; ++q) {
            v2f g01 = *reinterpret_cast<const v2f*>(wsp + B_OFF + 4 * q);
            v2f g23 = *reinterpret_cast<const v2f*>(wsp + B_OFF + 4 * q + 2);
            g01 = g01 + x0v * *reinterpret_cast<const v2f*>(wsp + WIH_OFF + 8 * q);
            g23 = g23 + x0v * *reinterpret_cast<const v2f*>(wsp + WIH_OFF + 8 * q + 2);
            g01 = g01 + x1v * *reinterpret_cast<const v2f*>(wsp + WIH_OFF + 8 * q + 4);
            g23 = g23 + x1v * *reinterpret_cast<const v2f*>(wsp + WIH_OFF + 8 * q + 6);
#pragma unroll
            for (int k = 0; k < H; ++k) {
                const v2f wp01 = *reinterpret_cast<const v2f*>(wsp + WHH_OFF + (q * 20 + k) * 4);
                const v2f wp23 = *reinterpret_cast<const v2f*>(wsp + WHH_OFF + (q * 20 + k) * 4 + 2);
                g01 = g01 + hv2[k] * wp01;
                g23 = g23 + hv2[k] * wp23;
            }
            const float gi = sigmoidf_stable(g01.x);
            const float gf = sigmoidf_stable(g01.y);
            const float gg = tanhf(g23.x);
            const float go = sigmoidf_stable(g23.y);
            const float cq = gf * cxr[q] + gi * gg;
            const float hq = go * tanhf(cq);
            l0e += hq * W_dec[q];
            l1e += hq * W_dec[20 + q];
            l2e += hq * W_dec[40 + q];
        }
        const float me = fmaxf(fmaxf(l0e, l1e), l2e);
        const float se = expf(l0e - me) + expf(l1e - me) + expf(l2e - me);
        const float lsee = me + logf(se);
        const float lp0e = l0e - lsee, lp1e = l1e - lsee, lp2e = l2e - lsee;
        const float p0e = expf(lp0e), p1e = expf(lp1e), p2e = expf(lp2e);
        const float c0e = p0e;
        const float c1e = c0e + p1e;
        const float c2e = c1e + p2e;
        int ae = (int)(c0e < uv) + (int)(c1e < uv) + (int)(c2e < uv);
        ae = ae > 2 ? 2 : ae;
        act = (float)ae;
        slp = (ae == 0) ? lp0e : ((ae == 1) ? lp1e : lp2e);
    }

    out[b] = act;
    out[(size_t)BATCH + b] = slp;

    __syncthreads();   // all h rows finalized in sT

    float* hout  = out + 2 * (size_t)BATCH;
    float* cout_ = hout + (size_t)H * BATCH;

    // ---- coalesced h store ----
#pragma unroll
    for (int j = 0; j < 5; ++j) {
        const int g = 4 * (t + BLK * j);
        float4 v;
#pragma unroll
        for (int e = 0; e < 4; ++e) {
            const int gg = g + e;
            (&v.x)[e] = sT[gg + gg / H];
        }
        *reinterpret_cast<float4*>(hout + base + g) = v;
    }
    __syncthreads();   // h-store reads done; safe to overwrite with c

#pragma unroll
    for (int k = 0; k < H; ++k) sT[row + k] = cv[k];
    __syncthreads();

    // ---- coalesced c store ----
#pragma unroll
    for (int j = 0; j < 5; ++j) {
        const int g = 4 * (t + BLK * j);
        float4 v;
#pragma unroll
        for (int e = 0; e < 4; ++e) {
            const int gg = g + e;
            (&v.x)[e] = sT[gg + gg / H];
        }
        *reinterpret_cast<float4*>(cout_ + base + g) = v;
    }
}

extern "C" void kernel_launch(void* const* d_in, const int* in_sizes, int n_in,
                              void* d_out, int out_size, void* d_ws, size_t ws_size,
                              hipStream_t stream) {
    const float* x     = (const float*)d_in[0];
    const float* hx    = (const float*)d_in[1];
    const float* cx    = (const float*)d_in[2];
    const float* u     = (const float*)d_in[3];
    const float* W_ih  = (const float*)d_in[4];
    const float* W_hh  = (const float*)d_in[5];
    const float* b_ih  = (const float*)d_in[6];
    const float* b_hh  = (const float*)d_in[7];
    const float* W_dec = (const float*)d_in[8];
    const float* b_dec = (const float*)d_in[9];
    float* out = (float*)d_out;
    float* ws  = (float*)d_ws;

    pack_weights<<<2, 256, 0, stream>>>(W_ih, W_hh, b_ih, b_hh, ws);

    dim3 grid(BATCH / BLK), block(BLK);
    lstm_coord_kernel<<<grid, block, 0, stream>>>(
        x, hx, cx, u, ws, W_dec, b_dec, out);
}

// Round 8
// 122.852 us; speedup vs baseline: 1.0359x; 1.0359x over previous
//
#include <hip/hip_runtime.h>

constexpr int BATCH = 1048576;
constexpr int H = 20;       // hidden
constexpr int BLK = 256;    // threads per block = batch rows per block
constexpr int RS = 21;      // padded LDS row stride (gcd(21,32)=1 -> conflict-free)
constexpr int TILE = BLK * H;   // 5120 floats per tile

// packed-weight layout in d_ws (floats) — identical to validated R5-R7:
constexpr int WHH_OFF = 0;
constexpr int WIH_OFF = 1600;
constexpr int B_OFF   = 1760;

typedef float v2f __attribute__((ext_vector_type(2)));
__device__ __forceinline__ v2f splat2(float s) { v2f r; r.x = s; r.y = s; return r; }

// ---- exact path (bit-compatible with validated R3/R5-R7 kernels) ----
__device__ __forceinline__ float sigmoidf_stable(float z) {
    const float e = expf(-fabsf(z));
    const float n = (z >= 0.0f) ? 1.0f : e;
    return n / (1.0f + e);
}

// ---- fast path: native exp / rcp (validated R6/R7) ----
__device__ __forceinline__ float fsigmoid(float z) {
    const float e = __expf(-z);
    return __builtin_amdgcn_rcpf(1.0f + e);
}
__device__ __forceinline__ float ftanh(float z) {
    const float e = __expf(2.0f * z);
    return 1.0f - 2.0f * __builtin_amdgcn_rcpf(e + 1.0f);
}

constexpr float EPS_GUARD = 1e-4f;

__global__ __launch_bounds__(256) void pack_weights(
    const float* __restrict__ W_ih, const float* __restrict__ W_hh,
    const float* __restrict__ b_ih, const float* __restrict__ b_hh,
    float* __restrict__ ws)
{
    const int i = blockIdx.x * 256 + threadIdx.x;
    if (i < 400) {
        const int q = i / 20, k = i % 20;
#pragma unroll
        for (int g = 0; g < 4; ++g)
            ws[WHH_OFF + i * 4 + g] = W_hh[(g * 20 + q) * 20 + k];
    }
    if (i < 20) {
#pragma unroll
        for (int g = 0; g < 4; ++g) {
            ws[WIH_OFF + i * 8 + g]     = W_ih[(g * 20 + i) * 2 + 0];
            ws[WIH_OFF + i * 8 + 4 + g] = W_ih[(g * 20 + i) * 2 + 1];
            ws[B_OFF   + i * 4 + g]     = b_ih[g * 20 + i] + b_hh[g * 20 + i];
        }
    }
}

__global__ __launch_bounds__(BLK) void lstm_coord_kernel(
    const float* __restrict__ x,
    const float* __restrict__ hx,
    const float* __restrict__ cx,
    const float* __restrict__ u,
    const float* __restrict__ wsp,
    const float* __restrict__ W_dec,
    const float* __restrict__ b_dec,
    float* __restrict__ out)
{
    // LDS used ONLY to coalesce the h/c output stores.
    __shared__ float sH[BLK * RS];
    __shared__ float sC[BLK * RS];

    const int t = threadIdx.x;
    const size_t base = (size_t)blockIdx.x * TILE;
    const int b = blockIdx.x * BLK + t;
    const int row = t * RS;

    // ---- direct per-row register loads (no LDS, no barriers) ----
    // Reads at 80B/lane stride: each 128B line still fetched once (wave span
    // is contiguous) -> traffic ideal; only WRITES need LDS coalescing (R0 lesson).
    const size_t rowbase = (size_t)b * H;
    v2f hv2[H];              // splatted for packed-FMA operand; live for fallback
    float cxv[H];
#pragma unroll
    for (int j = 0; j < 5; ++j) {
        const float4 hh = *reinterpret_cast<const float4*>(hx + rowbase + 4 * j);
        hv2[4 * j + 0] = splat2(hh.x); hv2[4 * j + 1] = splat2(hh.y);
        hv2[4 * j + 2] = splat2(hh.z); hv2[4 * j + 3] = splat2(hh.w);
        const float4 cc = *reinterpret_cast<const float4*>(cx + rowbase + 4 * j);
        cxv[4 * j + 0] = cc.x; cxv[4 * j + 1] = cc.y;
        cxv[4 * j + 2] = cc.z; cxv[4 * j + 3] = cc.w;
    }
    const float2 xv = *reinterpret_cast<const float2*>(x + 2 * (size_t)b);
    const v2f x0v = splat2(xv.x);
    const v2f x1v = splat2(xv.y);
    const float uv = u[b];

    // ---- FAST path: LSTM cell + fused decode (bit-identical arithmetic
    //      and accumulation ORDER to validated R5-R7) ----
    float l0 = b_dec[0], l1 = b_dec[1], l2 = b_dec[2];
#pragma unroll
    for (int q = 0; q < H; ++q) {
        v2f g01 = *reinterpret_cast<const v2f*>(wsp + B_OFF + 4 * q);
        v2f g23 = *reinterpret_cast<const v2f*>(wsp + B_OFF + 4 * q + 2);
        g01 = g01 + x0v * *reinterpret_cast<const v2f*>(wsp + WIH_OFF + 8 * q);
        g23 = g23 + x0v * *reinterpret_cast<const v2f*>(wsp + WIH_OFF + 8 * q + 2);
        g01 = g01 + x1v * *reinterpret_cast<const v2f*>(wsp + WIH_OFF + 8 * q + 4);
        g23 = g23 + x1v * *reinterpret_cast<const v2f*>(wsp + WIH_OFF + 8 * q + 6);
#pragma unroll
        for (int k = 0; k < H; ++k) {
            const v2f wp01 = *reinterpret_cast<const v2f*>(wsp + WHH_OFF + (q * 20 + k) * 4);
            const v2f wp23 = *reinterpret_cast<const v2f*>(wsp + WHH_OFF + (q * 20 + k) * 4 + 2);
            g01 = g01 + hv2[k] * wp01;
            g23 = g23 + hv2[k] * wp23;
        }
        const float gi = fsigmoid(g01.x);
        const float gf = fsigmoid(g01.y);
        const float gg = ftanh(g23.x);
        const float go = fsigmoid(g23.y);
        const float cq = gf * cxv[q] + gi * gg;
        const float hq = go * ftanh(cq);
        sC[row + q] = cq;       // own row only
        sH[row + q] = hq;       // own row only
        l0 += hq * W_dec[q];
        l1 += hq * W_dec[20 + q];
        l2 += hq * W_dec[40 + q];
    }

    // ---- fast softmax + inverse-CDF sample ----
    const float m = fmaxf(fmaxf(l0, l1), l2);
    const float s = __expf(l0 - m) + __expf(l1 - m) + __expf(l2 - m);
    const float lse = m + __logf(s);
    const float lp0 = l0 - lse, lp1 = l1 - lse, lp2 = l2 - lse;
    const float p0 = __expf(lp0), p1 = __expf(lp1), p2 = __expf(lp2);
    const float c0 = p0;
    const float c1 = c0 + p1;
    const float c2 = c1 + p2;
    int acti = (int)(c0 < uv) + (int)(c1 < uv) + (int)(c2 < uv);
    acti = acti > 2 ? 2 : acti;
    float act = (float)acti;
    float slp = (acti == 0) ? lp0 : ((acti == 1) ? lp1 : lp2);

    // ---- guard: near a fast-cdf boundary -> redo with exact libm path ----
    const float d0 = fabsf(c0 - uv), d1 = fabsf(c1 - uv), d2 = fabsf(c2 - uv);
    const bool risky = fminf(fminf(d0, d1), d2) < EPS_GUARD;
    if (risky) {
        const float* cxr = cx + rowbase;   // original cx
        float l0e = b_dec[0], l1e = b_dec[1], l2e = b_dec[2];
#pragma unroll 1
        for (int q = 0; q < H; ++q) {
            v2f g01 = *reinterpret_cast<const v2f*>(wsp + B_OFF + 4 * q);
            v2f g23 = *reinterpret_cast<const v2f*>(wsp + B_OFF + 4 * q + 2);
            g01 = g01 + x0v * *reinterpret_cast<const v2f*>(wsp + WIH_OFF + 8 * q);
            g23 = g23 + x0v * *reinterpret_cast<const v2f*>(wsp + WIH_OFF + 8 * q + 2);
            g01 = g01 + x1v * *reinterpret_cast<const v2f*>(wsp + WIH_OFF + 8 * q + 4);
            g23 = g23 + x1v * *reinterpret_cast<const v2f*>(wsp + WIH_OFF + 8 * q + 6);
#pragma unroll
            for (int k = 0; k < H; ++k) {
                const v2f wp01 = *reinterpret_cast<const v2f*>(wsp + WHH_OFF + (q * 20 + k) * 4);
                const v2f wp23 = *reinterpret_cast<const v2f*>(wsp + WHH_OFF + (q * 20 + k) * 4 + 2);
                g01 = g01 + hv2[k] * wp01;
                g23 = g23 + hv2[k] * wp23;
            }
            const float gi = sigmoidf_stable(g01.x);
            const float gf = sigmoidf_stable(g01.y);
            const float gg = tanhf(g23.x);
            const float go = sigmoidf_stable(g23.y);
            const float cq = gf * cxr[q] + gi * gg;
            const float hq = go * tanhf(cq);
            l0e += hq * W_dec[q];
            l1e += hq * W_dec[20 + q];
            l2e += hq * W_dec[40 + q];
        }
        const float me = fmaxf(fmaxf(l0e, l1e), l2e);
        const float se = expf(l0e - me) + expf(l1e - me) + expf(l2e - me);
        const float lsee = me + logf(se);
        const float lp0e = l0e - lsee, lp1e = l1e - lsee, lp2e = l2e - lsee;
        const float p0e = expf(lp0e), p1e = expf(lp1e), p2e = expf(lp2e);
        const float c0e = p0e;
        const float c1e = c0e + p1e;
        const float c2e = c1e + p2e;
        int ae = (int)(c0e < uv) + (int)(c1e < uv) + (int)(c2e < uv);
        ae = ae > 2 ? 2 : ae;
        act = (float)ae;
        slp = (ae == 0) ? lp0e : ((ae == 1) ? lp1e : lp2e);
    }

    out[b] = act;
    out[(size_t)BATCH + b] = slp;

    __syncthreads();   // all rows of sH/sC finalized

    // ---- coalesced LDS->global stores of h/c tiles (verbatim R6) ----
    float* hout  = out + 2 * (size_t)BATCH;
    float* cout_ = hout + (size_t)H * BATCH;
#pragma unroll
    for (int j = 0; j < 5; ++j) {
        const int g = 4 * (t + BLK * j);
        float4 v, w;
#pragma unroll
        for (int e = 0; e < 4; ++e) {
            const int gg = g + e;
            (&v.x)[e] = sH[gg + gg / H];
            (&w.x)[e] = sC[gg + gg / H];
        }
        *reinterpret_cast<float4*>(hout  + base + g) = v;
        *reinterpret_cast<float4*>(cout_ + base + g) = w;
    }
}

extern "C" void kernel_launch(void* const* d_in, const int* in_sizes, int n_in,
                              void* d_out, int out_size, void* d_ws, size_t ws_size,
                              hipStream_t stream) {
    const float* x     = (const float*)d_in[0];
    const float* hx    = (const float*)d_in[1];
    const float* cx    = (const float*)d_in[2];
    const float* u     = (const float*)d_in[3];
    const float* W_ih  = (const float*)d_in[4];
    const float* W_hh  = (const float*)d_in[5];
    const float* b_ih  = (const float*)d_in[6];
    const float* b_hh  = (const float*)d_in[7];
    const float* W_dec = (const float*)d_in[8];
    const float* b_dec = (const float*)d_in[9];
    float* out = (float*)d_out;
    float* ws  = (float*)d_ws;

    pack_weights<<<2, 256, 0, stream>>>(W_ih, W_hh, b_ih, b_hh, ws);

    dim3 grid(BATCH / BLK), block(BLK);
    lstm_coord_kernel<<<grid, block, 0, stream>>>(
        x, hx, cx, u, ws, W_dec, b_dec, out);
}